// Round 3
// baseline (11285.566 us; speedup 1.0000x reference)
//
#include <hip/hip_runtime.h>
#include <hip/hip_bf16.h>

#define Bsz 32
#define Tn  64
#define Vn  32000
#define En  300
#define Hn  512
#define NFn 128
#define Dn  32
#define G4  2048
#define LIN 332
#define NWG 128

// workspace offsets (float units)
#define OFF_MPROJ 0
#define OFF_E0    (OFF_MPROJ + 131072)     /* fp32 [64][2048][32] */
#define OFF_PG0T  (OFF_E0 + 4194304)       /* fp32 [2048][32] j-major */
#define OFF_H1T   (OFF_PG0T + 65536)
#define OFF_H2T0  (OFF_H1T + 16384)
#define OFF_H2T1  (OFF_H2T0 + 16384)
#define OFF_H2B   (OFF_H2T1 + 16384)
#define OFF_C1T   (OFF_H2B + 16384)
#define OFF_C2T   (OFF_C1T + 16384)
#define OFF_BAR   (OFF_C2T + 16384)
#define OFF_MKEY  (OFF_BAR + 16)           /* fp32 [32][128][512] */
#define OFF_WHT   (OFF_MKEY + 2097152)     /* fp32 [512][512] k-major */
#define OFF_WCTX  (OFF_WHT + 262144)       /* fp32 [2048][32] */
#define OFF_X     (OFF_WCTX + 65536)       /* fp32 [2048][320] */
#define OFF_W0    (OFF_X + 655360)         /* fp32 [2048][320] */
#define OFF_HBF   (OFF_W0 + 655360)        /* bf16 [2048][512] */
#define OFF_FCWBF (OFF_HBF + 524288)       /* bf16 [32000][512] */

// output offsets (float units)
#define OUT_HF  65536000
#define OUT_CF  65568768
#define OUT_ATT 65601536

typedef __attribute__((ext_vector_type(8))) short short8;
typedef __attribute__((ext_vector_type(4))) float f32x4;
typedef unsigned short u16;

__device__ __forceinline__ float frcp(float x){ return __builtin_amdgcn_rcpf(x); }
__device__ __forceinline__ float ftanh(float x){
  float e = __expf(2.0f*x);
  return 1.0f - 2.0f*frcp(e+1.0f);
}
__device__ __forceinline__ float fsig(float x){
  return frcp(1.0f + __expf(-x));
}
__device__ __forceinline__ u16 f2bf(float f){
  __hip_bfloat16 h = __float2bfloat16(f);
  u16 r; __builtin_memcpy(&r, &h, 2); return r;
}

// ---------------- P1: midi_proj (f32) + midi_key (f32) ----------------
__global__ __launch_bounds__(1024) void p1_midi(
    const float* __restrict__ midi, const float* __restrict__ mp_w,
    const float* __restrict__ mp_b, const float* __restrict__ wm,
    float* __restrict__ ws)
{
  __shared__ float ms[NFn*Dn];
  __shared__ float pj[NFn*33];
  __shared__ float mpw[Dn*33];
  __shared__ float mpb[Dn];
  int b = blockIdx.x, tid = threadIdx.x;
  for (int i=tid;i<NFn*Dn;i+=1024) ms[i] = midi[b*NFn*Dn + i];
  { int e = tid>>5, d = tid&31; mpw[e*33+d] = mp_w[tid]; }
  if (tid < Dn) mpb[tid] = mp_b[tid];
  __syncthreads();
  float* mproj = ws + OFF_MPROJ;
  for (int i=tid;i<NFn*Dn;i+=1024){
    int f = i>>5, e = i&31;
    float a = mpb[e];
    #pragma unroll
    for (int d=0;d<Dn;d++) a += ms[f*32+d]*mpw[e*33+d];
    a = fmaxf(a, 0.0f);
    pj[f*33+e] = a;
    mproj[b*NFn*Dn + i] = a;
  }
  __syncthreads();
  int h = tid & 511, fh = tid >> 9;
  float wreg[32];
  #pragma unroll
  for (int d=0;d<32;d++) wreg[d] = wm[h*32+d];
  float* mkf = ws + OFF_MKEY + b*(NFn*Hn);
  for (int ff=0; ff<64; ff++){
    int f = fh*64 + ff;
    float a = 0.f;
    #pragma unroll
    for (int d=0;d<32;d++) a += pj[f*33+d]*wreg[d];
    mkf[f*512 + h] = a;
  }
}

// ---------------- P2a: gather embeddings -> f32 X[2048][320] ----------------
__global__ __launch_bounds__(256) void p2a_x(
    const int* __restrict__ seq, const float* __restrict__ emb,
    float* __restrict__ ws)
{
  int idx = blockIdx.x*256 + threadIdx.x;   // 640*256 = 163840 float4s
  int bt = idx / 80, c4 = idx - bt*80;
  int b = bt & 31, t = bt >> 5;
  float4 x = {0.f,0.f,0.f,0.f};
  if (c4 < 75){
    int s = seq[b*Tn + t];
    x = *(const float4*)(emb + (long)s*En + c4*4);
  }
  *(float4*)(ws + OFF_X + bt*320 + c4*4) = x;
}

// ---------------- P2b: wih0[:, :300] -> f32 [2048][320] padded ----------------
__global__ __launch_bounds__(256) void p2b_w(
    const float* __restrict__ wih0, float* __restrict__ ws)
{
  int idx = blockIdx.x*256 + threadIdx.x;   // 163840
  int j = idx / 80, c4 = idx - j*80;
  float4 x = {0.f,0.f,0.f,0.f};
  if (c4 < 75) x = *(const float4*)(wih0 + (long)j*LIN + c4*4);
  *(float4*)(ws + OFF_W0 + j*320 + c4*4) = x;
}

// ---------------- P2c: E0 = W0 @ X^T + bias (fp32 SGEMM 128x128x32) ----------------
__global__ __launch_bounds__(256) void p2c_e0(
    const float* __restrict__ ws_c, const float* __restrict__ bih0,
    const float* __restrict__ bhh0, float* __restrict__ ws)
{
  const float* A  = ws_c + OFF_W0;   // [2048][320]
  const float* Bm = ws_c + OFF_X;    // [2048][320]
  __shared__ float Al[32][132];      // [k][m]
  __shared__ float Bl[32][132];      // [k][n]
  int tid = threadIdx.x;
  int j0t = blockIdx.x*128, bt0 = blockIdx.y*128;
  int tx = tid & 15, ty = tid >> 4;
  float acc[8][8];
  #pragma unroll
  for (int i=0;i<8;i++)
    #pragma unroll
    for (int j=0;j<8;j++) acc[i][j] = 0.f;

  int m = tid >> 1;
  int kq = (tid & 1) * 16;
  for (int kk=0; kk<320; kk+=32){
    __syncthreads();
    {
      const float* As = A  + (long)(j0t+m)*320 + kk + kq;
      const float* Bs = Bm + (long)(bt0+m)*320 + kk + kq;
      float4 a0 = *(const float4*)(As+0), a1 = *(const float4*)(As+4);
      float4 a2 = *(const float4*)(As+8), a3 = *(const float4*)(As+12);
      float4 b0 = *(const float4*)(Bs+0), b1 = *(const float4*)(Bs+4);
      float4 b2 = *(const float4*)(Bs+8), b3 = *(const float4*)(Bs+12);
      Al[kq+0][m]=a0.x; Al[kq+1][m]=a0.y; Al[kq+2][m]=a0.z; Al[kq+3][m]=a0.w;
      Al[kq+4][m]=a1.x; Al[kq+5][m]=a1.y; Al[kq+6][m]=a1.z; Al[kq+7][m]=a1.w;
      Al[kq+8][m]=a2.x; Al[kq+9][m]=a2.y; Al[kq+10][m]=a2.z; Al[kq+11][m]=a2.w;
      Al[kq+12][m]=a3.x; Al[kq+13][m]=a3.y; Al[kq+14][m]=a3.z; Al[kq+15][m]=a3.w;
      Bl[kq+0][m]=b0.x; Bl[kq+1][m]=b0.y; Bl[kq+2][m]=b0.z; Bl[kq+3][m]=b0.w;
      Bl[kq+4][m]=b1.x; Bl[kq+5][m]=b1.y; Bl[kq+6][m]=b1.z; Bl[kq+7][m]=b1.w;
      Bl[kq+8][m]=b2.x; Bl[kq+9][m]=b2.y; Bl[kq+10][m]=b2.z; Bl[kq+11][m]=b2.w;
      Bl[kq+12][m]=b3.x; Bl[kq+13][m]=b3.y; Bl[kq+14][m]=b3.z; Bl[kq+15][m]=b3.w;
    }
    __syncthreads();
    #pragma unroll 4
    for (int k=0;k<32;k++){
      float4 a0 = *(const float4*)&Al[k][ty*8];
      float4 a1 = *(const float4*)&Al[k][ty*8+4];
      float4 b0 = *(const float4*)&Bl[k][tx*8];
      float4 b1 = *(const float4*)&Bl[k][tx*8+4];
      float av[8] = {a0.x,a0.y,a0.z,a0.w,a1.x,a1.y,a1.z,a1.w};
      float bv[8] = {b0.x,b0.y,b0.z,b0.w,b1.x,b1.y,b1.z,b1.w};
      #pragma unroll
      for (int i=0;i<8;i++)
        #pragma unroll
        for (int j=0;j<8;j++) acc[i][j] += av[i]*bv[j];
    }
  }
  float* E0 = ws + OFF_E0;
  #pragma unroll
  for (int i=0;i<8;i++){
    int j = j0t + ty*8 + i;
    float be = bih0[j] + bhh0[j];
    #pragma unroll
    for (int jj=0;jj<8;jj++){
      int c = bt0 + tx*8 + jj;
      int tt = c >> 5, bb = c & 31;
      E0[tt*65536 + j*32 + bb] = acc[i][jj] + be;
    }
  }
}

// ---------------- P3: fc_w -> bf16 ----------------
__global__ __launch_bounds__(256) void p3_cvt(
    const float* __restrict__ fcw, float* __restrict__ ws)
{
  u16* dst = (u16*)(ws + OFF_FCWBF);
  int base = (blockIdx.x*256 + threadIdx.x)*8;
  float4 x = *(const float4*)(fcw+base);
  float4 y = *(const float4*)(fcw+base+4);
  short8 p;
  p[0]=(short)f2bf(x.x); p[1]=(short)f2bf(x.y); p[2]=(short)f2bf(x.z); p[3]=(short)f2bf(x.w);
  p[4]=(short)f2bf(y.x); p[5]=(short)f2bf(y.y); p[6]=(short)f2bf(y.z); p[7]=(short)f2bf(y.w);
  *(short8*)(dst+base) = p;
}

// ---------------- P4: wh -> whT f32 [512][512] (k-major) ----------------
__global__ __launch_bounds__(256) void p4_wht(
    const float* __restrict__ wh, float* __restrict__ ws)
{
  int k = blockIdx.x, tid = threadIdx.x;
  float* W = ws + OFF_WHT;
  W[k*512 + tid]       = wh[tid*512 + k];
  W[k*512 + tid + 256] = wh[(tid+256)*512 + k];
}

// ---------------- P5: wih0[:,300:332] -> f32 [2048][32] ----------------
__global__ __launch_bounds__(256) void p5_wctx(
    const float* __restrict__ wih0, float* __restrict__ ws)
{
  int idx = blockIdx.x*256 + threadIdx.x;   // 65536
  int j = idx >> 5, d = idx & 31;
  ws[OFF_WCTX + idx] = wih0[(long)j*LIN + En + d];
}

// ---------------- P0: zero states, pg0T = E0[0], bar=0 ----------------
__global__ __launch_bounds__(256) void p0_init(float* __restrict__ ws){
  int idx = blockIdx.x*256 + threadIdx.x;   // 65536
  ws[OFF_PG0T + idx] = ws[OFF_E0 + idx];
  if (idx < 16384){
    ws[OFF_H1T+idx]=0.f; ws[OFF_H2T0+idx]=0.f; ws[OFF_H2T1+idx]=0.f;
    ws[OFF_H2B+idx]=0.f; ws[OFF_C1T+idx]=0.f; ws[OFF_C2T+idx]=0.f;
  }
  if (idx == 0) *(unsigned*)(ws + OFF_BAR) = 0u;
}

// ---------------- grid barrier ----------------
__device__ __forceinline__ void gbar(unsigned* bar, unsigned target){
  __syncthreads();
  if (threadIdx.x == 0){
    __threadfence();
    __hip_atomic_fetch_add(bar, 1u, __ATOMIC_ACQ_REL, __HIP_MEMORY_SCOPE_AGENT);
    unsigned cnt = 0;
    while (__hip_atomic_load(bar, __ATOMIC_ACQUIRE, __HIP_MEMORY_SCOPE_AGENT) < target){
      __builtin_amdgcn_s_sleep(2);
      if (++cnt >= (1u<<18)) break;   // safety: terminate rather than hang
    }
    __threadfence();
  }
  __syncthreads();
  asm volatile("" ::: "memory");
}

// ---------------- fused 64-step scan (128 WGs) ----------------
__global__ __launch_bounds__(1024) void scan_all(
    const float* __restrict__ wih1, const float* __restrict__ whh1,
    const float* __restrict__ whh0, const float* __restrict__ bih1,
    const float* __restrict__ bhh1, const float* __restrict__ vvec,
    float* __restrict__ ws, float* __restrict__ out)
{
  __shared__ float h2l[512], ql[512], vl[512];
  __shared__ float qpart[8][512];
  __shared__ float scl[128], atl[128];
  __shared__ float ptl[32*33];
  __shared__ float ctxl[32];
  __shared__ float gsh[4][512];
  __shared__ float gl[16][32];

  const int wg = blockIdx.x, tid = threadIdx.x;
  unsigned* bar = (unsigned*)(ws + OFF_BAR);
  const float* mkey = ws + OFF_MKEY;
  const float* whtf = ws + OFF_WHT;
  const float* wctxf = ws + OFF_WCTX;
  float* h1T  = ws + OFF_H1T;
  float* h2B  = ws + OFF_H2B;
  float* c1T  = ws + OFF_C1T;
  float* c2T  = ws + OFF_C2T;
  float* pg0T = ws + OFF_PG0T;
  u16*   hbf  = (u16*)(ws + OFF_HBF);

  if (wg < 32 && tid < 512) vl[tid] = vvec[tid];
  unsigned gen = 0;

  for (int t=0; t<64; t++){
    // ================= phase A: attention + LSTM0 (32 b-WGs) =================
    if (wg < 32){
      const int b = wg;
      if (tid < 512) h2l[tid] = h2B[b*512 + tid];
      __syncthreads();
      // q[h] = whT[:,h] . h2 (8 k-slices x 128 h-quads)
      {
        int hq = tid & 127, ks = tid >> 7;
        const float4* wq = (const float4*)whtf;
        float a0=0,a1=0,a2=0,a3=0;
        int k0 = ks*64;
        #pragma unroll 8
        for (int k=k0; k<k0+64; k++){
          float4 w = wq[k*128 + hq];
          float hk = h2l[k];
          a0 += w.x*hk; a1 += w.y*hk; a2 += w.z*hk; a3 += w.w*hk;
        }
        qpart[ks][hq*4+0]=a0; qpart[ks][hq*4+1]=a1;
        qpart[ks][hq*4+2]=a2; qpart[ks][hq*4+3]=a3;
      }
      __syncthreads();
      if (tid < 512){
        float s = 0.f;
        #pragma unroll
        for (int ks=0;ks<8;ks++) s += qpart[ks][tid];
        ql[tid] = s;
      }
      __syncthreads();
      // scores: 16 waves x 8 f, lane covers h = l*8..l*8+7
      {
        int wv = tid >> 6, l = tid & 63;
        float qq[8], vv[8];
        #pragma unroll
        for (int j=0;j<8;j++){ qq[j]=ql[l*8+j]; vv[j]=vl[l*8+j]; }
        const float* mkb = mkey + b*65536;
        for (int ff=0; ff<8; ff++){
          int f = wv*8 + ff;
          const float* mkf = mkb + f*512 + l*8;
          float4 k0 = *(const float4*)(mkf);
          float4 k1 = *(const float4*)(mkf+4);
          float kvf[8] = {k0.x,k0.y,k0.z,k0.w,k1.x,k1.y,k1.z,k1.w};
          float s = 0.f;
          #pragma unroll
          for (int j=0;j<8;j++) s += vv[j]*ftanh(qq[j] + kvf[j]);
          #pragma unroll
          for (int m=1;m<64;m<<=1) s += __shfl_xor(s, m, 64);
          if (l==0) scl[f] = s;
        }
      }
      __syncthreads();
      if (tid < 64){
        float s0 = scl[tid], s1 = scl[tid+64];
        float mx = fmaxf(s0,s1);
        #pragma unroll
        for (int m=1;m<64;m<<=1) mx = fmaxf(mx, __shfl_xor(mx,m,64));
        float e0 = __expf(s0-mx), e1 = __expf(s1-mx);
        float sm = e0+e1;
        #pragma unroll
        for (int m=1;m<64;m<<=1) sm += __shfl_xor(sm,m,64);
        float inv = frcp(sm);
        float a0=e0*inv, a1=e1*inv;
        atl[tid]=a0; atl[tid+64]=a1;
        float* oa = out + OUT_ATT + b*(Tn*NFn) + t*NFn;
        oa[tid]=a0; oa[tid+64]=a1;
      }
      __syncthreads();
      // ctx[d] = sum_f attn[f]*mproj[f][d]
      {
        int d = tid & 31, g = tid >> 5;
        const float* mp = ws + OFF_MPROJ + b*(NFn*Dn);
        float p = 0.f;
        #pragma unroll
        for (int q=0;q<4;q++){ int f = g*4+q; p += atl[f]*mp[f*32+d]; }
        ptl[d*33+g] = p;
      }
      __syncthreads();
      if (tid < 32){
        float s = 0.f;
        #pragma unroll
        for (int g=0;g<32;g++) s += ptl[tid*33+g];
        ctxl[tid] = s;
      }
      __syncthreads();
      // gates0 = pg0T + wctx @ ctx
      {
        int k = tid & 511, qh = tid >> 9;
        #pragma unroll
        for (int qi=0; qi<2; qi++){
          int q = qh*2 + qi;
          int j = q*512 + k;
          float acc = pg0T[j*32 + b];
          const float* wr = wctxf + j*32;
          #pragma unroll
          for (int d=0; d<32; d+=4){
            float4 w4 = *(const float4*)(wr + d);
            acc += w4.x*ctxl[d]+w4.y*ctxl[d+1]+w4.z*ctxl[d+2]+w4.w*ctxl[d+3];
          }
          gsh[q][k] = acc;
        }
      }
      __syncthreads();
      if (tid < 512){
        int k = tid;
        float cp = c1T[k*32+b];
        float cn = fsig(gsh[1][k])*cp + fsig(gsh[0][k])*ftanh(gsh[2][k]);
        float hn = fsig(gsh[3][k])*ftanh(cn);
        c1T[k*32+b] = cn; h1T[k*32+b] = hn;
        if (t==63){ out[OUT_HF + b*512 + k]=hn; out[OUT_CF + b*512 + k]=cn; }
      }
    }
    gen++; gbar(bar, gen*NWG);
    // ================= phase B: LSTM1 gates + cells + pg0 next =================
    {
      const float* h2r = ws + ((t&1) ? OFF_H2T1 : OFF_H2T0);
      float* h2w       = ws + ((t&1) ? OFF_H2T0 : OFF_H2T1);
      int r = tid >> 5, b = tid & 31;
      if (r < 16){
        int g = r >> 2, i = r & 3;
        int row = g*512 + wg*4 + i;
        const float* wa  = wih1 + (long)row*512;
        const float* wb2 = whh1 + (long)row*512;
        float acc = 0.f;
        #pragma unroll 2
        for (int kk=0; kk<512; kk+=4){
          float4 a4 = *(const float4*)(wa+kk);
          float4 b4 = *(const float4*)(wb2+kk);
          float x0 = h1T[(kk+0)*32+b], x1 = h1T[(kk+1)*32+b];
          float x2 = h1T[(kk+2)*32+b], x3 = h1T[(kk+3)*32+b];
          float y0 = h2r[(kk+0)*32+b], y1 = h2r[(kk+1)*32+b];
          float y2 = h2r[(kk+2)*32+b], y3 = h2r[(kk+3)*32+b];
          acc += a4.x*x0 + a4.y*x1 + a4.z*x2 + a4.w*x3;
          acc += b4.x*y0 + b4.y*y1 + b4.z*y2 + b4.w*y3;
        }
        gl[r][b] = acc + bih1[row] + bhh1[row];
      } else if (t < 63){
        int i2 = r - 16;
        int row2 = wg*16 + i2;
        const float* wc = whh0 + (long)row2*512;
        float pacc = 0.f;
        #pragma unroll 2
        for (int kk=0; kk<512; kk+=4){
          float4 c4 = *(const float4*)(wc+kk);
          pacc += c4.x*h1T[(kk+0)*32+b] + c4.y*h1T[(kk+1)*32+b]
                + c4.z*h1T[(kk+2)*32+b] + c4.w*h1T[(kk+3)*32+b];
        }
        pg0T[row2*32 + b] = pacc + ws[OFF_E0 + (t+1)*65536 + row2*32 + b];
      }
      __syncthreads();
      if (tid < 128){
        int kl = tid >> 5, b2 = tid & 31;
        int k2 = wg*4 + kl;
        float gi = gl[0*4+kl][b2], gf = gl[1*4+kl][b2];
        float gg = gl[2*4+kl][b2], go = gl[3*4+kl][b2];
        float cp = c2T[k2*32+b2];
        float cn = fsig(gf)*cp + fsig(gi)*ftanh(gg);
        float hn = fsig(go)*ftanh(cn);
        c2T[k2*32+b2] = cn;
        h2w[k2*32+b2] = hn;
        h2B[b2*512+k2] = hn;
        hbf[(t*32+b2)*512 + k2] = f2bf(hn);
        if (t==63){ out[OUT_HF + 16384 + b2*512 + k2]=hn; out[OUT_CF + 16384 + b2*512 + k2]=cn; }
      }
    }
    if (t < 63){ gen++; gbar(bar, gen*NWG); }
  }
}

// ---------------- FC: logits = h @ fc_w^T + fc_b (bf16 MFMA) ----------------
__global__ __launch_bounds__(256) void fc_gemm(
    const float* __restrict__ ws_f, const float* __restrict__ fcb,
    float* __restrict__ out)
{
  const u16* A  = (const u16*)(ws_f + OFF_FCWBF);   // [32000][512] fc_w
  const u16* Bm = (const u16*)(ws_f + OFF_HBF);     // [2048][512] h (bt-major)
  __shared__ u16 Al[128*40];
  __shared__ u16 Bl[128*40];
  int tid = threadIdx.x;
  int v0 = blockIdx.x*128, bt0 = blockIdx.y*128;
  int lane = tid & 63, wv = tid >> 6;
  int wr = wv >> 1, wc = wv & 1;
  f32x4 acc[4][4];
  #pragma unroll
  for (int i=0;i<4;i++)
    #pragma unroll
    for (int j=0;j<4;j++) acc[i][j] = (f32x4){0.f,0.f,0.f,0.f};

  int ar = wr*64 + (lane&15);
  int br = wc*64 + (lane&15);
  int ks = (lane>>4)*8;

  for (int kk=0; kk<512; kk+=32){
    __syncthreads();
    #pragma unroll
    for (int i=0;i<2;i++){
      int ld = tid + 256*i;
      int row = ld >> 2, cs = (ld & 3)*8;
      *(int4*)(&Al[row*40+cs]) = *(const int4*)(A  + (v0+row)*512 + kk + cs);
      *(int4*)(&Bl[row*40+cs]) = *(const int4*)(Bm + (bt0+row)*512 + kk + cs);
    }
    __syncthreads();
    short8 af[4], bf[4];
    #pragma unroll
    for (int m=0;m<4;m++) af[m] = *(const short8*)(&Al[(ar+m*16)*40 + ks]);
    #pragma unroll
    for (int n=0;n<4;n++) bf[n] = *(const short8*)(&Bl[(br+n*16)*40 + ks]);
    #pragma unroll
    for (int m=0;m<4;m++)
      #pragma unroll
      for (int n=0;n<4;n++)
        acc[m][n] = __builtin_amdgcn_mfma_f32_16x16x32_bf16(af[m], bf[n], acc[m][n], 0,0,0);
  }
  int r4 = (lane>>4)*4;
  #pragma unroll
  for (int m=0;m<4;m++){
    int v = v0 + wr*64 + m*16 + r4;
    float4 bias = *(const float4*)(fcb + v);
    #pragma unroll
    for (int n=0;n<4;n++){
      int bt = bt0 + wc*64 + n*16 + (lane&15);
      int b = bt & 31, t = bt >> 5;
      f32x4 a = acc[m][n];
      float4 res = { a[0]+bias.x, a[1]+bias.y, a[2]+bias.z, a[3]+bias.w };
      *(float4*)(out + b*2048000 + t*32000 + v) = res;
    }
  }
}

extern "C" void kernel_launch(void* const* d_in, const int* in_sizes, int n_in,
                              void* d_out, int out_size, void* d_ws, size_t ws_size,
                              hipStream_t stream)
{
  const int*   seq  = (const int*)d_in[0];
  const float* midi = (const float*)d_in[1];
  const float* emb  = (const float*)d_in[2];
  const float* mpw  = (const float*)d_in[3];
  const float* mpb  = (const float*)d_in[4];
  const float* wh   = (const float*)d_in[5];
  const float* wm   = (const float*)d_in[6];
  const float* vv   = (const float*)d_in[7];
  const float* wih0 = (const float*)d_in[8];
  const float* whh0 = (const float*)d_in[9];
  const float* bih0 = (const float*)d_in[10];
  const float* bhh0 = (const float*)d_in[11];
  const float* wih1 = (const float*)d_in[12];
  const float* whh1 = (const float*)d_in[13];
  const float* bih1 = (const float*)d_in[14];
  const float* bhh1 = (const float*)d_in[15];
  const float* fcw  = (const float*)d_in[16];
  const float* fcb  = (const float*)d_in[17];
  float* out = (float*)d_out;
  float* ws  = (float*)d_ws;

  p1_midi<<<32, 1024, 0, stream>>>(midi, mpw, mpb, wm, ws);
  p2a_x  <<<640, 256, 0, stream>>>(seq, emb, ws);
  p2b_w  <<<640, 256, 0, stream>>>(wih0, ws);
  p2c_e0 <<<dim3(16,16), 256, 0, stream>>>(ws, bih0, bhh0, ws);
  p3_cvt <<<8000, 256, 0, stream>>>(fcw, ws);
  p4_wht <<<512, 256, 0, stream>>>(wh, ws);
  p5_wctx<<<256, 256, 0, stream>>>(wih0, ws);
  p0_init<<<256, 256, 0, stream>>>(ws);

  scan_all<<<NWG, 1024, 0, stream>>>(wih1, whh1, whh0, bih1, bhh1, vv, ws, out);

  fc_gemm<<<dim3(250,16), 256, 0, stream>>>(ws, fcb, out);
}

// Round 4
// 6445.346 us; speedup vs baseline: 1.7510x; 1.7510x over previous
//
#include <hip/hip_runtime.h>
#include <hip/hip_bf16.h>

#define Bsz 32
#define Tn  64
#define Vn  32000
#define En  300
#define Hn  512
#define NFn 128
#define Dn  32
#define G4  2048
#define LIN 332
#define NWG 128
#define SCAN_LDS_BYTES 149568

// workspace offsets (float units)
#define OFF_MPROJ 0
#define OFF_E0    (OFF_MPROJ + 131072)     /* fp32 [64][2048][32] */
#define OFF_PG0B  (OFF_E0 + 4194304)       /* fp32 [32][2048] b-major */
#define OFF_H1T   (OFF_PG0B + 65536)       /* fp32 [512][32] */
#define OFF_H2T0  (OFF_H1T + 16384)
#define OFF_H2T1  (OFF_H2T0 + 16384)
#define OFF_H2BB  (OFF_H2T1 + 16384)       /* fp32 [32][512] b-major */
#define OFF_C1T   (OFF_H2BB + 16384)
#define OFF_C2T   (OFF_C1T + 16384)
#define OFF_BAR   (OFF_C2T + 16384)
#define OFF_MKEY  (OFF_BAR + 16)           /* fp32 [32][128][512] */
#define OFF_WHT   (OFF_MKEY + 2097152)     /* fp32 [512][512] k-major */
#define OFF_WCTX  (OFF_WHT + 262144)       /* fp32 [2048][32] */
#define OFF_X     (OFF_WCTX + 65536)       /* fp32 [2048][320]; HBF reuses this after p2c */
#define OFF_W0    (OFF_X + 655360)         /* fp32 [2048][320] */
#define OFF_HBF   OFF_X                    /* bf16 [2048][512] (X dead after p2c) */
#define OFF_FCWBF (OFF_X + 524288)         /* bf16 [32000][512] (X/W0 dead; p3 runs after p2c) */

// output offsets (float units)
#define OUT_HF  65536000
#define OUT_CF  65568768
#define OUT_ATT 65601536

typedef __attribute__((ext_vector_type(8))) short short8;
typedef __attribute__((ext_vector_type(4))) float f32x4;
typedef unsigned short u16;

__device__ __forceinline__ float frcp(float x){ return __builtin_amdgcn_rcpf(x); }
__device__ __forceinline__ float ftanh(float x){
  float e = __expf(2.0f*x);
  return 1.0f - 2.0f*frcp(e+1.0f);
}
__device__ __forceinline__ float fsig(float x){
  return frcp(1.0f + __expf(-x));
}
__device__ __forceinline__ u16 f2bf(float f){
  __hip_bfloat16 h = __float2bfloat16(f);
  u16 r; __builtin_memcpy(&r, &h, 2); return r;
}

// ---- coherent (Infinity-Cache) access helpers: bypass non-coherent L1/L2,
// NEVER invalidate caches (keeps read-only weights L2-resident) ----
__device__ __forceinline__ float ldc1(const float* p){
  return __hip_atomic_load(p, __ATOMIC_RELAXED, __HIP_MEMORY_SCOPE_AGENT);
}
__device__ __forceinline__ void stc1(float* p, float v){
  __hip_atomic_store(p, v, __ATOMIC_RELAXED, __HIP_MEMORY_SCOPE_AGENT);
}
__device__ __forceinline__ float4 ldc4(const float* p){
  float4 r;
  asm volatile("global_load_dwordx4 %0, %1, off sc0 sc1"
               : "=v"(r) : "v"(p) : "memory");
  return r;
}
__device__ __forceinline__ void vwait(){
  asm volatile("s_waitcnt vmcnt(0)" ::: "memory");
  __builtin_amdgcn_sched_barrier(0);
}

// ---------------- P1: midi_proj (f32) + midi_key (f32) ----------------
__global__ __launch_bounds__(1024) void p1_midi(
    const float* __restrict__ midi, const float* __restrict__ mp_w,
    const float* __restrict__ mp_b, const float* __restrict__ wm,
    float* __restrict__ ws)
{
  __shared__ float ms[NFn*Dn];
  __shared__ float pj[NFn*33];
  __shared__ float mpw[Dn*33];
  __shared__ float mpb[Dn];
  int b = blockIdx.x, tid = threadIdx.x;
  for (int i=tid;i<NFn*Dn;i+=1024) ms[i] = midi[b*NFn*Dn + i];
  { int e = tid>>5, d = tid&31; mpw[e*33+d] = mp_w[tid]; }
  if (tid < Dn) mpb[tid] = mp_b[tid];
  __syncthreads();
  float* mproj = ws + OFF_MPROJ;
  for (int i=tid;i<NFn*Dn;i+=1024){
    int f = i>>5, e = i&31;
    float a = mpb[e];
    #pragma unroll
    for (int d=0;d<Dn;d++) a += ms[f*32+d]*mpw[e*33+d];
    a = fmaxf(a, 0.0f);
    pj[f*33+e] = a;
    mproj[b*NFn*Dn + i] = a;
  }
  __syncthreads();
  int h = tid & 511, fh = tid >> 9;
  float wreg[32];
  #pragma unroll
  for (int d=0;d<32;d++) wreg[d] = wm[h*32+d];
  float* mkf = ws + OFF_MKEY + b*(NFn*Hn);
  for (int ff=0; ff<64; ff++){
    int f = fh*64 + ff;
    float a = 0.f;
    #pragma unroll
    for (int d=0;d<32;d++) a += pj[f*33+d]*wreg[d];
    mkf[f*512 + h] = a;
  }
}

// ---------------- P2a: gather embeddings -> f32 X[2048][320] ----------------
__global__ __launch_bounds__(256) void p2a_x(
    const int* __restrict__ seq, const float* __restrict__ emb,
    float* __restrict__ ws)
{
  int idx = blockIdx.x*256 + threadIdx.x;   // 640*256 = 163840 float4s
  int bt = idx / 80, c4 = idx - bt*80;
  int b = bt & 31, t = bt >> 5;
  float4 x = {0.f,0.f,0.f,0.f};
  if (c4 < 75){
    int s = seq[b*Tn + t];
    x = *(const float4*)(emb + (long)s*En + c4*4);
  }
  *(float4*)(ws + OFF_X + bt*320 + c4*4) = x;
}

// ---------------- P2b: wih0[:, :300] -> f32 [2048][320] padded ----------------
__global__ __launch_bounds__(256) void p2b_w(
    const float* __restrict__ wih0, float* __restrict__ ws)
{
  int idx = blockIdx.x*256 + threadIdx.x;   // 163840
  int j = idx / 80, c4 = idx - j*80;
  float4 x = {0.f,0.f,0.f,0.f};
  if (c4 < 75) x = *(const float4*)(wih0 + (long)j*LIN + c4*4);
  *(float4*)(ws + OFF_W0 + j*320 + c4*4) = x;
}

// ---------------- P2c: E0 = W0 @ X^T + bias (fp32 SGEMM 128x128x32) ----------------
__global__ __launch_bounds__(256) void p2c_e0(
    const float* __restrict__ ws_c, const float* __restrict__ bih0,
    const float* __restrict__ bhh0, float* __restrict__ ws)
{
  const float* A  = ws_c + OFF_W0;   // [2048][320]
  const float* Bm = ws_c + OFF_X;    // [2048][320]
  __shared__ float Al[32][132];      // [k][m]
  __shared__ float Bl[32][132];      // [k][n]
  int tid = threadIdx.x;
  int j0t = blockIdx.x*128, bt0 = blockIdx.y*128;
  int tx = tid & 15, ty = tid >> 4;
  float acc[8][8];
  #pragma unroll
  for (int i=0;i<8;i++)
    #pragma unroll
    for (int j=0;j<8;j++) acc[i][j] = 0.f;

  int m = tid >> 1;
  int kq = (tid & 1) * 16;
  for (int kk=0; kk<320; kk+=32){
    __syncthreads();
    {
      const float* As = A  + (long)(j0t+m)*320 + kk + kq;
      const float* Bs = Bm + (long)(bt0+m)*320 + kk + kq;
      float4 a0 = *(const float4*)(As+0), a1 = *(const float4*)(As+4);
      float4 a2 = *(const float4*)(As+8), a3 = *(const float4*)(As+12);
      float4 b0 = *(const float4*)(Bs+0), b1 = *(const float4*)(Bs+4);
      float4 b2 = *(const float4*)(Bs+8), b3 = *(const float4*)(Bs+12);
      Al[kq+0][m]=a0.x; Al[kq+1][m]=a0.y; Al[kq+2][m]=a0.z; Al[kq+3][m]=a0.w;
      Al[kq+4][m]=a1.x; Al[kq+5][m]=a1.y; Al[kq+6][m]=a1.z; Al[kq+7][m]=a1.w;
      Al[kq+8][m]=a2.x; Al[kq+9][m]=a2.y; Al[kq+10][m]=a2.z; Al[kq+11][m]=a2.w;
      Al[kq+12][m]=a3.x; Al[kq+13][m]=a3.y; Al[kq+14][m]=a3.z; Al[kq+15][m]=a3.w;
      Bl[kq+0][m]=b0.x; Bl[kq+1][m]=b0.y; Bl[kq+2][m]=b0.z; Bl[kq+3][m]=b0.w;
      Bl[kq+4][m]=b1.x; Bl[kq+5][m]=b1.y; Bl[kq+6][m]=b1.z; Bl[kq+7][m]=b1.w;
      Bl[kq+8][m]=b2.x; Bl[kq+9][m]=b2.y; Bl[kq+10][m]=b2.z; Bl[kq+11][m]=b2.w;
      Bl[kq+12][m]=b3.x; Bl[kq+13][m]=b3.y; Bl[kq+14][m]=b3.z; Bl[kq+15][m]=b3.w;
    }
    __syncthreads();
    #pragma unroll 4
    for (int k=0;k<32;k++){
      float4 a0 = *(const float4*)&Al[k][ty*8];
      float4 a1 = *(const float4*)&Al[k][ty*8+4];
      float4 b0 = *(const float4*)&Bl[k][tx*8];
      float4 b1 = *(const float4*)&Bl[k][tx*8+4];
      float av[8] = {a0.x,a0.y,a0.z,a0.w,a1.x,a1.y,a1.z,a1.w};
      float bv[8] = {b0.x,b0.y,b0.z,b0.w,b1.x,b1.y,b1.z,b1.w};
      #pragma unroll
      for (int i=0;i<8;i++)
        #pragma unroll
        for (int j=0;j<8;j++) acc[i][j] += av[i]*bv[j];
    }
  }
  float* E0 = ws + OFF_E0;
  #pragma unroll
  for (int i=0;i<8;i++){
    int j = j0t + ty*8 + i;
    float be = bih0[j] + bhh0[j];
    #pragma unroll
    for (int jj=0;jj<8;jj++){
      int c = bt0 + tx*8 + jj;
      int tt = c >> 5, bb = c & 31;
      E0[tt*65536 + j*32 + bb] = acc[i][jj] + be;
    }
  }
}

// ---------------- P3: fc_w -> bf16 ----------------
__global__ __launch_bounds__(256) void p3_cvt(
    const float* __restrict__ fcw, float* __restrict__ ws)
{
  u16* dst = (u16*)(ws + OFF_FCWBF);
  int base = (blockIdx.x*256 + threadIdx.x)*8;
  float4 x = *(const float4*)(fcw+base);
  float4 y = *(const float4*)(fcw+base+4);
  short8 p;
  p[0]=(short)f2bf(x.x); p[1]=(short)f2bf(x.y); p[2]=(short)f2bf(x.z); p[3]=(short)f2bf(x.w);
  p[4]=(short)f2bf(y.x); p[5]=(short)f2bf(y.y); p[6]=(short)f2bf(y.z); p[7]=(short)f2bf(y.w);
  *(short8*)(dst+base) = p;
}

// ---------------- P4: wh -> whT f32 [512][512] (k-major) ----------------
__global__ __launch_bounds__(256) void p4_wht(
    const float* __restrict__ wh, float* __restrict__ ws)
{
  int k = blockIdx.x, tid = threadIdx.x;
  float* W = ws + OFF_WHT;
  W[k*512 + tid]       = wh[tid*512 + k];
  W[k*512 + tid + 256] = wh[(tid+256)*512 + k];
}

// ---------------- P5: wih0[:,300:332] -> f32 [2048][32] ----------------
__global__ __launch_bounds__(256) void p5_wctx(
    const float* __restrict__ wih0, float* __restrict__ ws)
{
  int idx = blockIdx.x*256 + threadIdx.x;   // 65536
  int j = idx >> 5, d = idx & 31;
  ws[OFF_WCTX + idx] = wih0[(long)j*LIN + En + d];
}

// ---------------- P0: zero states, pg0B = E0[0]^T(b-major), bar=0 ----------------
__global__ __launch_bounds__(256) void p0_init(float* __restrict__ ws){
  int idx = blockIdx.x*256 + threadIdx.x;   // 65536
  int b = idx >> 11, j = idx & 2047;
  ws[OFF_PG0B + idx] = ws[OFF_E0 + j*32 + b];
  if (idx < 16384){
    ws[OFF_H1T+idx]=0.f; ws[OFF_H2T0+idx]=0.f; ws[OFF_H2T1+idx]=0.f;
    ws[OFF_H2BB+idx]=0.f; ws[OFF_C1T+idx]=0.f; ws[OFF_C2T+idx]=0.f;
  }
  if (idx == 0) *(unsigned*)(ws + OFF_BAR) = 0u;
}

// ---------------- grid barrier: NO fences, NO L2 invalidation ----------------
__device__ __forceinline__ void gbar(unsigned* bar, unsigned target){
  __syncthreads();   // implicit vmcnt(0): all write-through stores at IC
  if (threadIdx.x == 0){
    __hip_atomic_fetch_add(bar, 1u, __ATOMIC_RELAXED, __HIP_MEMORY_SCOPE_AGENT);
    unsigned cnt = 0;
    while (__hip_atomic_load(bar, __ATOMIC_RELAXED, __HIP_MEMORY_SCOPE_AGENT) < target){
      __builtin_amdgcn_s_sleep(1);
      if (++cnt >= (1u<<20)) break;   // safety: terminate rather than hang
    }
  }
  __syncthreads();
  asm volatile("" ::: "memory");
}

// 64-lane reduce-scatter of acc[8][4] (rows x b) over the lane(=k-slice) dim.
// Returns the full sum for (ro,bo) derived from lane bits.
__device__ __forceinline__ float redux(float (&acc)[8][4], int L, int& ro, int& bo){
  float a4[4][4];
  #pragma unroll
  for (int r=0;r<4;r++)
    #pragma unroll
    for (int j=0;j<4;j++){
      float send = (L&32)? acc[r][j]   : acc[r+4][j];
      float keep = (L&32)? acc[r+4][j] : acc[r][j];
      a4[r][j] = keep + __shfl_xor(send, 32, 64);
    }
  float a2[2][4];
  #pragma unroll
  for (int r=0;r<2;r++)
    #pragma unroll
    for (int j=0;j<4;j++){
      float send = (L&16)? a4[r][j]   : a4[r+2][j];
      float keep = (L&16)? a4[r+2][j] : a4[r][j];
      a2[r][j] = keep + __shfl_xor(send, 16, 64);
    }
  float a1[4];
  #pragma unroll
  for (int j=0;j<4;j++){
    float send = (L&8)? a2[0][j] : a2[1][j];
    float keep = (L&8)? a2[1][j] : a2[0][j];
    a1[j] = keep + __shfl_xor(send, 8, 64);
  }
  float b2v[2];
  #pragma unroll
  for (int jj=0;jj<2;jj++){
    float send = (L&4)? a1[jj]   : a1[2+jj];
    float keep = (L&4)? a1[2+jj] : a1[jj];
    b2v[jj] = keep + __shfl_xor(send, 4, 64);
  }
  float b1;
  {
    float send = (L&2)? b2v[0] : b2v[1];
    float keep = (L&2)? b2v[1] : b2v[0];
    b1 = keep + __shfl_xor(send, 2, 64);
  }
  float v = b1 + __shfl_xor(b1, 1, 64);
  ro = ((L>>5)&1)*4 + ((L>>4)&1)*2 + ((L>>3)&1);
  bo = ((L>>2)&1)*2 + ((L>>1)&1);
  return v;
}

// ---------------- fused 64-step scan (128 WGs, dynamic LDS) ----------------
__global__ __launch_bounds__(1024) void scan_all(
    const float* __restrict__ wih1, const float* __restrict__ whh1,
    const float* __restrict__ whh0, const float* __restrict__ bih1,
    const float* __restrict__ bhh1, const float* __restrict__ vvec,
    float* __restrict__ ws, float* __restrict__ out)
{
  extern __shared__ float lds[];
  const int wg = blockIdx.x, tid = threadIdx.x;
  unsigned* bar = (unsigned*)(ws + OFF_BAR);
  const float* mkey  = ws + OFF_MKEY;
  const float* whtf  = ws + OFF_WHT;
  const float* wctxf = ws + OFF_WCTX;
  float* h1T  = ws + OFF_H1T;
  float* h2Bb = ws + OFF_H2BB;
  float* c1T  = ws + OFF_C1T;
  float* c2T  = ws + OFF_C2T;
  float* pg0B = ws + OFF_PG0B;
  u16*   hbf  = (u16*)(ws + OFF_HBF);
  unsigned gen = 0;

  for (int t=0; t<64; t++){
    // ================= phase A: attention + LSTM0 (32 b-WGs) =================
    if (wg < 32){
      const int b = wg;
      float* h2l = lds;               // [512]
      float* ql  = lds + 512;         // [512]
      float (*qpart)[512] = (float(*)[512])(lds + 1024);   // [8][512]
      float* scl  = lds + 5120;       // [128]
      float* atl  = lds + 5248;       // [128]
      float* ptl  = lds + 5376;       // [1056]
      float* ctxl = lds + 6432;       // [32]
      float (*gsh)[512] = (float(*)[512])(lds + 6464);     // [4][512]
      if (tid < 512) h2l[tid] = ldc1(h2Bb + b*512 + tid);
      __syncthreads();
      // q[h] = whT[:,h] . h2 (8 k-slices x 128 h-quads)
      {
        int hq = tid & 127, ks = tid >> 7;
        const float4* wq = (const float4*)whtf;
        float a0=0,a1=0,a2=0,a3=0;
        int k0 = ks*64;
        #pragma unroll 8
        for (int k=k0; k<k0+64; k++){
          float4 w = wq[k*128 + hq];
          float hk = h2l[k];
          a0 += w.x*hk; a1 += w.y*hk; a2 += w.z*hk; a3 += w.w*hk;
        }
        qpart[ks][hq*4+0]=a0; qpart[ks][hq*4+1]=a1;
        qpart[ks][hq*4+2]=a2; qpart[ks][hq*4+3]=a3;
      }
      __syncthreads();
      if (tid < 512){
        float s = 0.f;
        #pragma unroll
        for (int ks=0;ks<8;ks++) s += qpart[ks][tid];
        ql[tid] = s;
      }
      __syncthreads();
      // scores: 16 waves x 8 f
      {
        int wv = tid >> 6, l = tid & 63;
        float qq[8], vv[8];
        #pragma unroll
        for (int j=0;j<8;j++){ qq[j]=ql[l*8+j]; vv[j]=vvec[l*8+j]; }
        const float* mkb = mkey + b*65536;
        for (int ff=0; ff<8; ff++){
          int f = wv*8 + ff;
          const float* mkf = mkb + f*512 + l*8;
          float4 k0 = *(const float4*)(mkf);
          float4 k1 = *(const float4*)(mkf+4);
          float kvf[8] = {k0.x,k0.y,k0.z,k0.w,k1.x,k1.y,k1.z,k1.w};
          float s = 0.f;
          #pragma unroll
          for (int j=0;j<8;j++) s += vv[j]*ftanh(qq[j] + kvf[j]);
          #pragma unroll
          for (int m=1;m<64;m<<=1) s += __shfl_xor(s, m, 64);
          if (l==0) scl[f] = s;
        }
      }
      __syncthreads();
      if (tid < 64){
        float s0 = scl[tid], s1 = scl[tid+64];
        float mx = fmaxf(s0,s1);
        #pragma unroll
        for (int m=1;m<64;m<<=1) mx = fmaxf(mx, __shfl_xor(mx,m,64));
        float e0 = __expf(s0-mx), e1 = __expf(s1-mx);
        float sm = e0+e1;
        #pragma unroll
        for (int m=1;m<64;m<<=1) sm += __shfl_xor(sm,m,64);
        float inv = frcp(sm);
        float a0=e0*inv, a1=e1*inv;
        atl[tid]=a0; atl[tid+64]=a1;
        float* oa = out + OUT_ATT + b*(Tn*NFn) + t*NFn;
        oa[tid]=a0; oa[tid+64]=a1;
      }
      __syncthreads();
      // ctx[d] = sum_f attn[f]*mproj[f][d]
      {
        int d = tid & 31, g = tid >> 5;
        const float* mp = ws + OFF_MPROJ + b*(NFn*Dn);
        float p = 0.f;
        #pragma unroll
        for (int q=0;q<4;q++){ int f = g*4+q; p += atl[f]*mp[f*32+d]; }
        ptl[d*33+g] = p;
      }
      __syncthreads();
      if (tid < 32){
        float s = 0.f;
        #pragma unroll
        for (int g=0;g<32;g++) s += ptl[tid*33+g];
        ctxl[tid] = s;
      }
      __syncthreads();
      // gates0 = pg0 + wctx @ ctx
      {
        int k = tid & 511, qh = tid >> 9;
        #pragma unroll
        for (int qi=0; qi<2; qi++){
          int q = qh*2 + qi;
          int j = q*512 + k;
          float acc = ldc1(pg0B + b*2048 + j);
          const float* wr = wctxf + j*32;
          #pragma unroll
          for (int d=0; d<32; d+=4){
            float4 w4 = *(const float4*)(wr + d);
            acc += w4.x*ctxl[d]+w4.y*ctxl[d+1]+w4.z*ctxl[d+2]+w4.w*ctxl[d+3];
          }
          gsh[q][k] = acc;
        }
      }
      __syncthreads();
      if (tid < 512){
        int k = tid;
        float cp = c1T[k*32+b];
        float cn = fsig(gsh[1][k])*cp + fsig(gsh[0][k])*ftanh(gsh[2][k]);
        float hn = fsig(gsh[3][k])*ftanh(cn);
        c1T[k*32+b] = cn;
        stc1(h1T + k*32 + b, hn);
        if (t==63){ out[OUT_HF + b*512 + k]=hn; out[OUT_CF + b*512 + k]=cn; }
      }
    }
    gen++; gbar(bar, gen*NWG);
    // ================= phase B: LSTM1 gates + cells + pg0 next (128 WGs) =================
    {
      const float* h2r = ws + ((t&1) ? OFF_H2T1 : OFF_H2T0);
      float* h2w       = ws + ((t&1) ? OFF_H2T0 : OFF_H2T1);
      float (*hs1)[36] = (float(*)[36])lds;             // [512][36]
      float (*hs2)[36] = (float(*)[36])(lds + 18432);   // [512][36]
      float (*gl)[33]  = (float(*)[33])(lds + 36864);   // [16][33]
      // stage h1 (new) and h2 (prev) into LDS via coherent loads
      {
        int g = tid & 7, k0 = tid >> 3;
        float4 r1[4], r2[4];
        #pragma unroll
        for (int it=0; it<4; ++it){
          r1[it] = ldc4(h1T + (k0 + it*128)*32 + g*4);
          r2[it] = ldc4(h2r + (k0 + it*128)*32 + g*4);
        }
        vwait();
        #pragma unroll
        for (int it=0; it<4; ++it){
          int k = k0 + it*128;
          hs1[k][g*4+0]=r1[it].x; hs1[k][g*4+1]=r1[it].y;
          hs1[k][g*4+2]=r1[it].z; hs1[k][g*4+3]=r1[it].w;
          hs2[k][g*4+0]=r2[it].x; hs2[k][g*4+1]=r2[it].y;
          hs2[k][g*4+2]=r2[it].z; hs2[k][g*4+3]=r2[it].w;
        }
      }
      __syncthreads();
      int w = tid >> 6, L = tid & 63;
      int rg = w >> 3, bq = w & 7;
      // gates1: 16 rows/WG, K=1024 (wih1.h1 | whh1.h2prev)
      {
        float acc[8][4];
        #pragma unroll
        for (int r=0;r<8;r++){ acc[r][0]=0;acc[r][1]=0;acc[r][2]=0;acc[r][3]=0; }
        #pragma unroll 4
        for (int i=0;i<16;i++){
          int k = i*64 + L;
          const float* hrow; const float* wbase; int kk;
          if (i<8){ kk = k; hrow = hs1[k]; wbase = wih1; }
          else    { kk = k-512; hrow = hs2[kk]; wbase = whh1; }
          float4 h4 = *(const float4*)&hrow[bq*4];
          #pragma unroll
          for (int r=0;r<8;r++){
            int rl = rg*8 + r;
            int row = ((rl>>2)<<9) + wg*4 + (rl&3);
            float wv = wbase[(long)row*512 + kk];
            acc[r][0] += wv*h4.x; acc[r][1] += wv*h4.y;
            acc[r][2] += wv*h4.z; acc[r][3] += wv*h4.w;
          }
        }
        int ro, bo;
        float v = redux(acc, L, ro, bo);
        int rl = rg*8 + ro;
        int b  = bq*4 + bo;
        int row = ((rl>>2)<<9) + wg*4 + (rl&3);
        gl[rl][b] = v + bih1[row] + bhh1[row];
      }
      // pg0 next: 16 rows/WG, K=512 (whh0.h1) + E0[t+1]
      if (t < 63){
        float acc[8][4];
        #pragma unroll
        for (int r=0;r<8;r++){ acc[r][0]=0;acc[r][1]=0;acc[r][2]=0;acc[r][3]=0; }
        #pragma unroll 4
        for (int i=0;i<8;i++){
          int k = i*64 + L;
          float4 h4 = *(const float4*)&hs1[k][bq*4];
          #pragma unroll
          for (int r=0;r<8;r++){
            int row2 = wg*16 + rg*8 + r;
            float wv = whh0[(long)row2*512 + k];
            acc[r][0] += wv*h4.x; acc[r][1] += wv*h4.y;
            acc[r][2] += wv*h4.z; acc[r][3] += wv*h4.w;
          }
        }
        int ro, bo;
        float v = redux(acc, L, ro, bo);
        int row2 = wg*16 + rg*8 + ro;
        int b    = bq*4 + bo;
        v += ws[OFF_E0 + (t+1)*65536 + row2*32 + b];
        stc1(pg0B + b*2048 + row2, v);
      }
      __syncthreads();
      if (tid < 128){
        int ii = tid >> 5, b2 = tid & 31;
        int k2 = wg*4 + ii;
        float gi = gl[(0<<2)|ii][b2], gf = gl[(1<<2)|ii][b2];
        float gg = gl[(2<<2)|ii][b2], go = gl[(3<<2)|ii][b2];
        float cp = c2T[k2*32+b2];
        float cn = fsig(gf)*cp + fsig(gi)*ftanh(gg);
        float hn = fsig(go)*ftanh(cn);
        c2T[k2*32+b2] = cn;
        stc1(h2w + k2*32 + b2, hn);
        stc1(h2Bb + b2*512 + k2, hn);
        hbf[(t*32+b2)*512 + k2] = f2bf(hn);
        if (t==63){ out[OUT_HF + 16384 + b2*512 + k2]=hn; out[OUT_CF + 16384 + b2*512 + k2]=cn; }
      }
    }
    if (t < 63){ gen++; gbar(bar, gen*NWG); }
  }
}

// ---------------- FC: logits = h @ fc_w^T + fc_b (bf16 MFMA) ----------------
__global__ __launch_bounds__(256) void fc_gemm(
    const float* __restrict__ ws_f, const float* __restrict__ fcb,
    float* __restrict__ out)
{
  const u16* A  = (const u16*)(ws_f + OFF_FCWBF);   // [32000][512] fc_w
  const u16* Bm = (const u16*)(ws_f + OFF_HBF);     // [2048][512] h (bt-major)
  __shared__ u16 Al[128*40];
  __shared__ u16 Bl[128*40];
  int tid = threadIdx.x;
  int v0 = blockIdx.x*128, bt0 = blockIdx.y*128;
  int lane = tid & 63, wv = tid >> 6;
  int wr = wv >> 1, wc = wv & 1;
  f32x4 acc[4][4];
  #pragma unroll
  for (int i=0;i<4;i++)
    #pragma unroll
    for (int j=0;j<4;j++) acc[i][j] = (f32x4){0.f,0.f,0.f,0.f};

  int ar = wr*64 + (lane&15);
  int br = wc*64 + (lane&15);
  int ks = (lane>>4)*8;

  for (int kk=0; kk<512; kk+=32){
    __syncthreads();
    #pragma unroll
    for (int i=0;i<2;i++){
      int ld = tid + 256*i;
      int row = ld >> 2, cs = (ld & 3)*8;
      *(int4*)(&Al[row*40+cs]) = *(const int4*)(A  + (v0+row)*512 + kk + cs);
      *(int4*)(&Bl[row*40+cs]) = *(const int4*)(Bm + (bt0+row)*512 + kk + cs);
    }
    __syncthreads();
    short8 af[4], bf[4];
    #pragma unroll
    for (int m=0;m<4;m++) af[m] = *(const short8*)(&Al[(ar+m*16)*40 + ks]);
    #pragma unroll
    for (int n=0;n<4;n++) bf[n] = *(const short8*)(&Bl[(br+n*16)*40 + ks]);
    #pragma unroll
    for (int m=0;m<4;m++)
      #pragma unroll
      for (int n=0;n<4;n++)
        acc[m][n] = __builtin_amdgcn_mfma_f32_16x16x32_bf16(af[m], bf[n], acc[m][n], 0,0,0);
  }
  int r4 = (lane>>4)*4;
  #pragma unroll
  for (int m=0;m<4;m++){
    int v = v0 + wr*64 + m*16 + r4;
    float4 bias = *(const float4*)(fcb + v);
    #pragma unroll
    for (int n=0;n<4;n++){
      int bt = bt0 + wc*64 + n*16 + (lane&15);
      int b = bt & 31, t = bt >> 5;
      f32x4 a = acc[m][n];
      float4 res = { a[0]+bias.x, a[1]+bias.y, a[2]+bias.z, a[3]+bias.w };
      *(float4*)(out + b*2048000 + t*32000 + v) = res;
    }
  }
}

extern "C" void kernel_launch(void* const* d_in, const int* in_sizes, int n_in,
                              void* d_out, int out_size, void* d_ws, size_t ws_size,
                              hipStream_t stream)
{
  const int*   seq  = (const int*)d_in[0];
  const float* midi = (const float*)d_in[1];
  const float* emb  = (const float*)d_in[2];
  const float* mpw  = (const float*)d_in[3];
  const float* mpb  = (const float*)d_in[4];
  const float* wh   = (const float*)d_in[5];
  const float* wm   = (const float*)d_in[6];
  const float* vv   = (const float*)d_in[7];
  const float* wih0 = (const float*)d_in[8];
  const float* whh0 = (const float*)d_in[9];
  const float* bih0 = (const float*)d_in[10];
  const float* bhh0 = (const float*)d_in[11];
  const float* wih1 = (const float*)d_in[12];
  const float* whh1 = (const float*)d_in[13];
  const float* bih1 = (const float*)d_in[14];
  const float* bhh1 = (const float*)d_in[15];
  const float* fcw  = (const float*)d_in[16];
  const float* fcb  = (const float*)d_in[17];
  float* out = (float*)d_out;
  float* ws  = (float*)d_ws;

  p1_midi<<<32, 1024, 0, stream>>>(midi, mpw, mpb, wm, ws);
  p2a_x  <<<640, 256, 0, stream>>>(seq, emb, ws);
  p2b_w  <<<640, 256, 0, stream>>>(wih0, ws);
  p2c_e0 <<<dim3(16,16), 256, 0, stream>>>(ws, bih0, bhh0, ws);
  p3_cvt <<<8000, 256, 0, stream>>>(fcw, ws);
  p4_wht <<<512, 256, 0, stream>>>(wh, ws);
  p5_wctx<<<256, 256, 0, stream>>>(wih0, ws);
  p0_init<<<256, 256, 0, stream>>>(ws);

  scan_all<<<NWG, 1024, SCAN_LDS_BYTES, stream>>>(wih1, whh1, whh0, bih1, bhh1, vv, ws, out);

  fc_gemm<<<dim3(250,16), 256, 0, stream>>>(ws, fcb, out);
}